// Round 6
// baseline (700.614 us; speedup 1.0000x reference)
//
#include <hip/hip_runtime.h>
#include <math.h>

#define NN 20000
#define EE 320000
#define RR 3
#define LL 3
#define HH 4
#define DD 64
#define CDIM 256   // H*D == IN
#define OUTD 128
#define NEG 0.2f

typedef float f32x4 __attribute__((ext_vector_type(4)));
typedef short sh8 __attribute__((ext_vector_type(8)));

__device__ __forceinline__ ushort f2bf(float f) {
    union { float f; uint u; } v; v.f = f;
    uint r = (v.u + 0x7FFF + ((v.u >> 16) & 1)) >> 16;   // RNE
    return (ushort)r;
}
__device__ __forceinline__ float bf2f(ushort u) {
    union { uint u; float f; } v; v.u = ((uint)u) << 16;
    return v.f;
}
__device__ __forceinline__ float bflo(uint p) { return bf2f((ushort)(p & 0xffff)); }
__device__ __forceinline__ float bfhi(uint p) { return bf2f((ushort)(p >> 16)); }

// ---------------- CSR build ----------------

__global__ void zero_ints(int* p, int n) {
    int i = blockIdx.x * blockDim.x + threadIdx.x;
    if (i < n) p[i] = 0;
}

__global__ void count_deg(const int* __restrict__ edge_dst, int* __restrict__ deg) {
    int i = blockIdx.x * blockDim.x + threadIdx.x;
    if (i >= RR * EE) return;
    int r = i / EE;
    atomicAdd(&deg[r * NN + edge_dst[i]], 1);
}

// one block per relation; wave-shfl scan, 3 barriers per 1024-chunk.
__global__ __launch_bounds__(1024) void scan_kernel(
    const int* __restrict__ deg, int* __restrict__ row_ptr) {
    int r = blockIdx.x;
    const int* d = deg + r * NN;
    int* rp = row_ptr + r * (NN + 1);
    __shared__ int wsum[16];
    int lane = threadIdx.x & 63, wv = threadIdx.x >> 6;
    if (threadIdx.x == 0) rp[0] = 0;
    int carry = 0;   // per-thread running total of previous chunks
    for (int base = 0; base < NN; base += 1024) {
        int i = base + threadIdx.x;
        int v = (i < NN) ? d[i] : 0;
        int s = v;
        #pragma unroll
        for (int off = 1; off < 64; off <<= 1) {
            int n = __shfl_up(s, off, 64);
            if (lane >= off) s += n;
        }
        if (lane == 63) wsum[wv] = s;
        __syncthreads();
        if (wv == 0) {
            int ws = (lane < 16) ? wsum[lane] : 0;
            #pragma unroll
            for (int off = 1; off < 16; off <<= 1) {
                int n = __shfl_up(ws, off, 64);
                if (lane >= off) ws += n;
            }
            if (lane < 16) wsum[lane] = ws;
        }
        __syncthreads();
        int incl = carry + (wv ? wsum[wv - 1] : 0) + s;
        if (i < NN) rp[i + 1] = incl;
        carry += wsum[15];
        __syncthreads();
    }
}

__global__ void fill_csr(const int* __restrict__ edge_src, const int* __restrict__ edge_dst,
                         const int* __restrict__ row_ptr, int* __restrict__ fill,
                         int* __restrict__ csr_src) {
    int i = blockIdx.x * blockDim.x + threadIdx.x;
    if (i >= RR * EE) return;
    int r = i / EE;
    int dst = edge_dst[i];
    int pos = atomicAdd(&fill[r * NN + dst], 1);
    csr_src[r * EE + row_ptr[r * (NN + 1) + dst] + pos] = edge_src[i];
}

// ---------------- dtype prep ----------------

__global__ void cvt_bf16x4(const float* __restrict__ in, ushort* __restrict__ out, int n4) {
    int i = blockIdx.x * blockDim.x + threadIdx.x;
    if (i >= n4) return;
    float4 v = *(const float4*)(in + (size_t)i * 4);
    ushort4 o;
    o.x = f2bf(v.x); o.y = f2bf(v.y); o.z = f2bf(v.z); o.w = f2bf(v.w);
    *(ushort4*)(out + (size_t)i * 4) = o;
}

// transpose [K][N] fp32 -> [N][K] bf16, one matrix per blockIdx.z
__global__ void prep_Wt(const float* __restrict__ W, ushort* __restrict__ Wt, int K, int N) {
    __shared__ float tile[32][33];
    int kb = blockIdx.x * 32, nb = blockIdx.y * 32;
    size_t base = (size_t)blockIdx.z * K * N;
    for (int yy = threadIdx.y; yy < 32; yy += 8)
        tile[yy][threadIdx.x] = W[base + (size_t)(kb + yy) * N + nb + threadIdx.x];
    __syncthreads();
    for (int yy = threadIdx.y; yy < 32; yy += 8)
        Wt[base + (size_t)(nb + yy) * K + kb + threadIdx.x] = f2bf(tile[threadIdx.x][yy]);
}

// ---------------- bf16 MFMA GEMM (+ fused el/er epilogue) ----------------

#define TM 128
#define TN 128
#define TK 32
#define LP 40   // LDS row pitch in bf16 elems (80 B: 16B-aligned, breaks 2^k bank stride)

__global__ __launch_bounds__(256) void gemm_bf16(
    const ushort* __restrict__ A, const ushort* __restrict__ Bt0, void* __restrict__ C0,
    int M, int K, int Ncol, long strideB, long strideC,
    const float* __restrict__ bias, int out_fp32,
    const float* __restrict__ al_all, const float* __restrict__ ar_all,
    float* __restrict__ el_all, float* __restrict__ er_all) {
    __shared__ alignas(16) ushort As[TM * LP];
    __shared__ alignas(16) ushort Bs[TN * LP];
    const ushort* Bt = Bt0 + (size_t)blockIdx.z * strideB;
    int m0 = blockIdx.x * TM, n0 = blockIdx.y * TN;
    int t = threadIdx.x;
    int wave = t >> 6, lane = t & 63;
    int q = lane >> 4, l16 = lane & 15;
    int wrow = (wave >> 1) * 64, wcol = (wave & 1) * 64;

    f32x4 acc[4][4];
    #pragma unroll
    for (int i = 0; i < 4; i++)
        #pragma unroll
        for (int j = 0; j < 4; j++)
            #pragma unroll
            for (int k = 0; k < 4; k++) acc[i][j][k] = 0.f;

    for (int k0 = 0; k0 < K; k0 += TK) {
        #pragma unroll
        for (int s = 0; s < 2; s++) {
            int qid = t + s * 256;
            int row = qid >> 2, kq = (qid & 3) * 8;
            uint4 v = make_uint4(0, 0, 0, 0);
            int gr = m0 + row;
            if (gr < M) v = *(const uint4*)(A + (size_t)gr * K + k0 + kq);
            *(uint4*)(As + row * LP + kq) = v;
        }
        #pragma unroll
        for (int s = 0; s < 2; s++) {
            int qid = t + s * 256;
            int row = qid >> 2, kq = (qid & 3) * 8;
            uint4 v = *(const uint4*)(Bt + (size_t)(n0 + row) * K + k0 + kq);
            *(uint4*)(Bs + row * LP + kq) = v;
        }
        __syncthreads();
        sh8 af[4], bfr[4];
        #pragma unroll
        for (int i = 0; i < 4; i++)
            af[i] = *(const sh8*)(As + (wrow + i * 16 + l16) * LP + q * 8);
        #pragma unroll
        for (int j = 0; j < 4; j++)
            bfr[j] = *(const sh8*)(Bs + (wcol + j * 16 + l16) * LP + q * 8);
        #pragma unroll
        for (int i = 0; i < 4; i++)
            #pragma unroll
            for (int j = 0; j < 4; j++)
                acc[i][j] = __builtin_amdgcn_mfma_f32_16x16x32_bf16(af[i], bfr[j], acc[i][j], 0, 0, 0);
        __syncthreads();
    }

    // epilogue: C/D layout col=lane&15, row=q*4+reg
    if (out_fp32) {
        float* C = (float*)C0 + (size_t)blockIdx.z * strideC;
        #pragma unroll
        for (int i = 0; i < 4; i++) {
            #pragma unroll
            for (int reg = 0; reg < 4; reg++) {
                int row = m0 + wrow + i * 16 + q * 4 + reg;
                if (row >= M) continue;
                #pragma unroll
                for (int j = 0; j < 4; j++) {
                    int col = n0 + wcol + j * 16 + l16;
                    float v = acc[i][j][reg];
                    if (bias) v += bias[col];
                    C[(size_t)row * Ncol + col] = v;
                }
            }
        }
    } else {
        ushort* C = (ushort*)C0 + (size_t)blockIdx.z * strideC;
        #pragma unroll
        for (int i = 0; i < 4; i++) {
            #pragma unroll
            for (int reg = 0; reg < 4; reg++) {
                int row = m0 + wrow + i * 16 + q * 4 + reg;
                if (row >= M) continue;
                #pragma unroll
                for (int j = 0; j < 4; j++) {
                    int col = n0 + wcol + j * 16 + l16;
                    C[(size_t)row * Ncol + col] = f2bf(acc[i][j][reg]);
                }
            }
        }
    }

    if (el_all) {
        const float* al = al_all + (size_t)blockIdx.z * CDIM;
        const float* ar = ar_all + (size_t)blockIdx.z * CDIM;
        float* elp = el_all + (size_t)blockIdx.z * NN * HH;
        float* erp = er_all + (size_t)blockIdx.z * NN * HH;
        int head = (n0 + wcol) >> 6;
        float alj[4], arj[4];
        #pragma unroll
        for (int j = 0; j < 4; j++) {
            int gcol = n0 + wcol + j * 16 + l16;
            alj[j] = al[gcol];
            arj[j] = ar[gcol];
        }
        #pragma unroll
        for (int i = 0; i < 4; i++) {
            #pragma unroll
            for (int reg = 0; reg < 4; reg++) {
                int row = m0 + wrow + i * 16 + q * 4 + reg;
                float pl = 0.f, pr = 0.f;
                #pragma unroll
                for (int j = 0; j < 4; j++) {
                    pl = fmaf(acc[i][j][reg], alj[j], pl);
                    pr = fmaf(acc[i][j][reg], arj[j], pr);
                }
                #pragma unroll
                for (int m = 1; m < 16; m <<= 1) {
                    pl += __shfl_xor(pl, m, 64);
                    pr += __shfl_xor(pr, m, 64);
                }
                if (l16 == 0 && row < M) {
                    elp[(size_t)row * HH + head] = pl;
                    erp[(size_t)row * HH + head] = pr;
                }
            }
        }
    }
}

// ---------------- fused softmax + aggregation ----------------
// wave per node (4 nodes/block); lane owns 4 channels (one uint2 = 8 B).
// Latency-oriented: 8-edge software pipeline (16 loads in flight), el fetched
// as wave-uniform float4 broadcast (1 cache line/edge instead of 4) with the
// per-head value selected in-register. Per-lane redundant exp is KEPT: on a
// SIMD the redundancy is free, and de-dup (r5) put shfl+gather on the
// critical path and regressed.
__global__ __launch_bounds__(256) void aggregate_fused(
    const ushort* __restrict__ feat16, const float* __restrict__ el,
    const float* __restrict__ er, const int* __restrict__ row_ptr,
    const int* __restrict__ csr_src, const float* __restrict__ bias,
    ushort* __restrict__ hout, int relu) {
    int wv = threadIdx.x >> 6, lane = threadIdx.x & 63;
    int node = blockIdx.x * 4 + wv;
    if (node >= NN) return;
    int c0 = lane * 4;
    int h = lane >> 4;
    float t0 = 0.f, t1 = 0.f, t2 = 0.f, t3 = 0.f;
    #pragma unroll
    for (int r = 0; r < RR; r++) {
        const int* rp = row_ptr + r * (NN + 1);
        int beg = rp[node], end = rp[node + 1];
        const ushort* fr = feat16 + (size_t)r * NN * CDIM;
        const float* elr = el + (size_t)r * NN * HH;
        float ern = er[((size_t)r * NN + node) * HH + h];
        const int* cs = csr_src + (size_t)r * EE;
        float p0 = 0.f, p1 = 0.f, p2 = 0.f, p3 = 0.f, ssum = 0.f;
        int e = beg;
        for (; e + 8 <= end; e += 8) {
            int s[8];
            #pragma unroll
            for (int k = 0; k < 8; k++) s[k] = cs[e + k];
            float4 eq[8];
            uint2 f[8];
            #pragma unroll
            for (int k = 0; k < 8; k++) eq[k] = *(const float4*)(elr + (size_t)s[k] * HH);
            #pragma unroll
            for (int k = 0; k < 8; k++) f[k] = *(const uint2*)(fr + (size_t)s[k] * CDIM + c0);
            #pragma unroll
            for (int k = 0; k < 8; k++) {
                float x = h < 2 ? (h == 0 ? eq[k].x : eq[k].y)
                                : (h == 2 ? eq[k].z : eq[k].w);
                x += ern;
                x = x > 0.f ? x : NEG * x;
                float a = __expf(x);
                ssum += a;
                p0 = fmaf(a, bflo(f[k].x), p0); p1 = fmaf(a, bfhi(f[k].x), p1);
                p2 = fmaf(a, bflo(f[k].y), p2); p3 = fmaf(a, bfhi(f[k].y), p3);
            }
        }
        for (; e < end; e++) {
            int s = cs[e];
            float4 eqs = *(const float4*)(elr + (size_t)s * HH);
            float x = h < 2 ? (h == 0 ? eqs.x : eqs.y)
                            : (h == 2 ? eqs.z : eqs.w);
            x += ern;
            x = x > 0.f ? x : NEG * x;
            float a = __expf(x);
            uint2 f = *(const uint2*)(fr + (size_t)s * CDIM + c0);
            ssum += a;
            p0 = fmaf(a, bflo(f.x), p0); p1 = fmaf(a, bfhi(f.x), p1);
            p2 = fmaf(a, bflo(f.y), p2); p3 = fmaf(a, bfhi(f.y), p3);
        }
        float is = (end > beg) ? 1.f / ssum : 0.f;
        t0 += p0 * is + bias[r * CDIM + c0];
        t1 += p1 * is + bias[r * CDIM + c0 + 1];
        t2 += p2 * is + bias[r * CDIM + c0 + 2];
        t3 += p3 * is + bias[r * CDIM + c0 + 3];
    }
    if (relu) {
        t0 = fmaxf(t0, 0.f); t1 = fmaxf(t1, 0.f);
        t2 = fmaxf(t2, 0.f); t3 = fmaxf(t3, 0.f);
    }
    uint2 o;
    o.x = (uint)f2bf(t0) | ((uint)f2bf(t1) << 16);
    o.y = (uint)f2bf(t2) | ((uint)f2bf(t3) << 16);
    *(uint2*)(hout + (size_t)node * CDIM + c0) = o;
}

// ---------------- launcher ----------------

extern "C" void kernel_launch(void* const* d_in, const int* in_sizes, int n_in,
                              void* d_out, int out_size, void* d_ws, size_t ws_size,
                              hipStream_t stream) {
    const float* x        = (const float*)d_in[0];
    const int*   edge_src = (const int*)d_in[1];
    const int*   edge_dst = (const int*)d_in[2];
    const float* W        = (const float*)d_in[3];
    const float* attn_l   = (const float*)d_in[4];
    const float* attn_r   = (const float*)d_in[5];
    const float* bias     = (const float*)d_in[6];
    const float* fc_w     = (const float*)d_in[7];
    const float* fc_b     = (const float*)d_in[8];
    float* out = (float*)d_out;

    char* ws = (char*)d_ws;
    size_t off = 0;
    auto alloc = [&](size_t bytes) {
        void* p = ws + off;
        off = (off + bytes + 255) & ~(size_t)255;
        return p;
    };
    ushort* x16    = (ushort*)alloc((size_t)NN * CDIM * 2);
    ushort* h16    = (ushort*)alloc((size_t)NN * CDIM * 2);
    ushort* feat16 = (ushort*)alloc((size_t)RR * NN * CDIM * 2);
    ushort* Wt16   = (ushort*)alloc((size_t)LL * RR * CDIM * CDIM * 2);
    ushort* fct16  = (ushort*)alloc((size_t)OUTD * CDIM * 2);
    float* el      = (float*)alloc((size_t)RR * NN * HH * 4);
    float* er      = (float*)alloc((size_t)RR * NN * HH * 4);
    int* row_ptr   = (int*)alloc((size_t)RR * (NN + 1) * 4);
    int* csr_src   = (int*)alloc((size_t)RR * EE * 4);
    int* deg       = (int*)alloc((size_t)2 * RR * NN * 4);
    int* fill      = deg + RR * NN;

    // CSR build
    zero_ints<<<dim3((2 * RR * NN + 1023) / 1024), dim3(1024), 0, stream>>>(deg, 2 * RR * NN);
    count_deg<<<dim3((RR * EE + 255) / 256), dim3(256), 0, stream>>>(edge_dst, deg);
    scan_kernel<<<dim3(RR), dim3(1024), 0, stream>>>(deg, row_ptr);
    fill_csr<<<dim3((RR * EE + 255) / 256), dim3(256), 0, stream>>>(edge_src, edge_dst, row_ptr, fill, csr_src);

    // dtype prep
    cvt_bf16x4<<<dim3((NN * CDIM / 4 + 255) / 256), dim3(256), 0, stream>>>(x, x16, NN * CDIM / 4);
    prep_Wt<<<dim3(CDIM / 32, CDIM / 32, LL * RR), dim3(32, 8), 0, stream>>>(W, Wt16, CDIM, CDIM);
    prep_Wt<<<dim3(CDIM / 32, OUTD / 32, 1), dim3(32, 8), 0, stream>>>(fc_w, fct16, CDIM, OUTD);

    const ushort* hin = x16;
    for (int l = 0; l < LL; l++) {
        const ushort* Wl = Wt16 + (size_t)l * RR * CDIM * CDIM;
        dim3 g((NN + TM - 1) / TM, CDIM / TN, RR);
        gemm_bf16<<<g, dim3(256), 0, stream>>>(hin, Wl, feat16, NN, CDIM, CDIM,
                                               (long)CDIM * CDIM, (long)NN * CDIM, nullptr, 0,
                                               attn_l + (size_t)l * RR * CDIM,
                                               attn_r + (size_t)l * RR * CDIM, el, er);
        aggregate_fused<<<dim3(NN / 4), dim3(256), 0, stream>>>(
            feat16, el, er, row_ptr, csr_src, bias + (size_t)l * RR * CDIM,
            h16, (l != LL - 1) ? 1 : 0);
        hin = h16;
    }
    dim3 gf((NN + TM - 1) / TM, OUTD / TN, 1);
    gemm_bf16<<<gf, dim3(256), 0, stream>>>(h16, fct16, out, NN, CDIM, OUTD,
                                            0, 0, fc_b, 1, nullptr, nullptr, nullptr, nullptr);
}

// Round 7
// 534.569 us; speedup vs baseline: 1.3106x; 1.3106x over previous
//
#include <hip/hip_runtime.h>
#include <math.h>

#define NN 20000
#define EE 320000
#define RR 3
#define LL 3
#define HH 4
#define DD 64
#define CDIM 256   // H*D == IN
#define OUTD 128
#define NEG 0.2f

typedef float f32x4 __attribute__((ext_vector_type(4)));
typedef short sh8 __attribute__((ext_vector_type(8)));

__device__ __forceinline__ ushort f2bf(float f) {
    union { float f; uint u; } v; v.f = f;
    uint r = (v.u + 0x7FFF + ((v.u >> 16) & 1)) >> 16;   // RNE
    return (ushort)r;
}
__device__ __forceinline__ float bf2f(ushort u) {
    union { uint u; float f; } v; v.u = ((uint)u) << 16;
    return v.f;
}
__device__ __forceinline__ float bflo(uint p) { return bf2f((ushort)(p & 0xffff)); }
__device__ __forceinline__ float bfhi(uint p) { return bf2f((ushort)(p >> 16)); }

// ---------------- CSR build ----------------

__global__ void zero_ints(int* p, int n) {
    int i = blockIdx.x * blockDim.x + threadIdx.x;
    if (i < n) p[i] = 0;
}

__global__ void count_deg(const int* __restrict__ edge_dst, int* __restrict__ deg) {
    int i = blockIdx.x * blockDim.x + threadIdx.x;
    if (i >= RR * EE) return;
    int r = i / EE;
    atomicAdd(&deg[r * NN + edge_dst[i]], 1);
}

// one block per relation; wave-shfl scan, 3 barriers per 1024-chunk.
__global__ __launch_bounds__(1024) void scan_kernel(
    const int* __restrict__ deg, int* __restrict__ row_ptr) {
    int r = blockIdx.x;
    const int* d = deg + r * NN;
    int* rp = row_ptr + r * (NN + 1);
    __shared__ int wsum[16];
    int lane = threadIdx.x & 63, wv = threadIdx.x >> 6;
    if (threadIdx.x == 0) rp[0] = 0;
    int carry = 0;   // per-thread running total of previous chunks
    for (int base = 0; base < NN; base += 1024) {
        int i = base + threadIdx.x;
        int v = (i < NN) ? d[i] : 0;
        int s = v;
        #pragma unroll
        for (int off = 1; off < 64; off <<= 1) {
            int n = __shfl_up(s, off, 64);
            if (lane >= off) s += n;
        }
        if (lane == 63) wsum[wv] = s;
        __syncthreads();
        if (wv == 0) {
            int ws = (lane < 16) ? wsum[lane] : 0;
            #pragma unroll
            for (int off = 1; off < 16; off <<= 1) {
                int n = __shfl_up(ws, off, 64);
                if (lane >= off) ws += n;
            }
            if (lane < 16) wsum[lane] = ws;
        }
        __syncthreads();
        int incl = carry + (wv ? wsum[wv - 1] : 0) + s;
        if (i < NN) rp[i + 1] = incl;
        carry += wsum[15];
        __syncthreads();
    }
}

// cursor[] starts as a copy of row_ptr; atomically bump to place each edge.
__global__ void fill_csr(const int* __restrict__ edge_src, const int* __restrict__ edge_dst,
                         int* __restrict__ cursor, int* __restrict__ csr_src) {
    int i = blockIdx.x * blockDim.x + threadIdx.x;
    if (i >= RR * EE) return;
    int r = i / EE;
    int dst = edge_dst[i];
    int pos = atomicAdd(&cursor[r * (NN + 1) + dst], 1);
    csr_src[r * EE + pos] = edge_src[i];
}

// ---------------- dtype prep ----------------

__global__ void cvt_bf16x4(const float* __restrict__ in, ushort* __restrict__ out, int n4) {
    int i = blockIdx.x * blockDim.x + threadIdx.x;
    if (i >= n4) return;
    float4 v = *(const float4*)(in + (size_t)i * 4);
    ushort4 o;
    o.x = f2bf(v.x); o.y = f2bf(v.y); o.z = f2bf(v.z); o.w = f2bf(v.w);
    *(ushort4*)(out + (size_t)i * 4) = o;
}

// transpose [K][N] fp32 -> [N][K] bf16, one matrix per blockIdx.z
__global__ void prep_Wt(const float* __restrict__ W, ushort* __restrict__ Wt, int K, int N) {
    __shared__ float tile[32][33];
    int kb = blockIdx.x * 32, nb = blockIdx.y * 32;
    size_t base = (size_t)blockIdx.z * K * N;
    for (int yy = threadIdx.y; yy < 32; yy += 8)
        tile[yy][threadIdx.x] = W[base + (size_t)(kb + yy) * N + nb + threadIdx.x];
    __syncthreads();
    for (int yy = threadIdx.y; yy < 32; yy += 8)
        Wt[base + (size_t)(nb + yy) * K + kb + threadIdx.x] = f2bf(tile[threadIdx.x][yy]);
}

// ---------------- bf16 MFMA GEMM (+ fused el/er epilogue) ----------------

#define TM 128
#define TN 128
#define TK 32
#define LP 40   // LDS row pitch in bf16 elems (80 B: 16B-aligned, breaks 2^k bank stride)

__global__ __launch_bounds__(256) void gemm_bf16(
    const ushort* __restrict__ A, const ushort* __restrict__ Bt0, void* __restrict__ C0,
    int M, int K, int Ncol, long strideB, long strideC,
    const float* __restrict__ bias, int out_fp32,
    const float* __restrict__ al_all, const float* __restrict__ ar_all,
    float* __restrict__ el_all, float* __restrict__ er_all) {
    __shared__ alignas(16) ushort As[TM * LP];
    __shared__ alignas(16) ushort Bs[TN * LP];
    const ushort* Bt = Bt0 + (size_t)blockIdx.z * strideB;
    int m0 = blockIdx.x * TM, n0 = blockIdx.y * TN;
    int t = threadIdx.x;
    int wave = t >> 6, lane = t & 63;
    int q = lane >> 4, l16 = lane & 15;
    int wrow = (wave >> 1) * 64, wcol = (wave & 1) * 64;

    f32x4 acc[4][4];
    #pragma unroll
    for (int i = 0; i < 4; i++)
        #pragma unroll
        for (int j = 0; j < 4; j++)
            #pragma unroll
            for (int k = 0; k < 4; k++) acc[i][j][k] = 0.f;

    for (int k0 = 0; k0 < K; k0 += TK) {
        #pragma unroll
        for (int s = 0; s < 2; s++) {
            int qid = t + s * 256;
            int row = qid >> 2, kq = (qid & 3) * 8;
            uint4 v = make_uint4(0, 0, 0, 0);
            int gr = m0 + row;
            if (gr < M) v = *(const uint4*)(A + (size_t)gr * K + k0 + kq);
            *(uint4*)(As + row * LP + kq) = v;
        }
        #pragma unroll
        for (int s = 0; s < 2; s++) {
            int qid = t + s * 256;
            int row = qid >> 2, kq = (qid & 3) * 8;
            uint4 v = *(const uint4*)(Bt + (size_t)(n0 + row) * K + k0 + kq);
            *(uint4*)(Bs + row * LP + kq) = v;
        }
        __syncthreads();
        sh8 af[4], bfr[4];
        #pragma unroll
        for (int i = 0; i < 4; i++)
            af[i] = *(const sh8*)(As + (wrow + i * 16 + l16) * LP + q * 8);
        #pragma unroll
        for (int j = 0; j < 4; j++)
            bfr[j] = *(const sh8*)(Bs + (wcol + j * 16 + l16) * LP + q * 8);
        #pragma unroll
        for (int i = 0; i < 4; i++)
            #pragma unroll
            for (int j = 0; j < 4; j++)
                acc[i][j] = __builtin_amdgcn_mfma_f32_16x16x32_bf16(af[i], bfr[j], acc[i][j], 0, 0, 0);
        __syncthreads();
    }

    // epilogue: C/D layout col=lane&15, row=q*4+reg
    if (out_fp32) {
        float* C = (float*)C0 + (size_t)blockIdx.z * strideC;
        #pragma unroll
        for (int i = 0; i < 4; i++) {
            #pragma unroll
            for (int reg = 0; reg < 4; reg++) {
                int row = m0 + wrow + i * 16 + q * 4 + reg;
                if (row >= M) continue;
                #pragma unroll
                for (int j = 0; j < 4; j++) {
                    int col = n0 + wcol + j * 16 + l16;
                    float v = acc[i][j][reg];
                    if (bias) v += bias[col];
                    C[(size_t)row * Ncol + col] = v;
                }
            }
        }
    } else {
        ushort* C = (ushort*)C0 + (size_t)blockIdx.z * strideC;
        #pragma unroll
        for (int i = 0; i < 4; i++) {
            #pragma unroll
            for (int reg = 0; reg < 4; reg++) {
                int row = m0 + wrow + i * 16 + q * 4 + reg;
                if (row >= M) continue;
                #pragma unroll
                for (int j = 0; j < 4; j++) {
                    int col = n0 + wcol + j * 16 + l16;
                    C[(size_t)row * Ncol + col] = f2bf(acc[i][j][reg]);
                }
            }
        }
    }

    if (el_all) {
        const float* al = al_all + (size_t)blockIdx.z * CDIM;
        const float* ar = ar_all + (size_t)blockIdx.z * CDIM;
        float* elp = el_all + (size_t)blockIdx.z * NN * HH;
        float* erp = er_all + (size_t)blockIdx.z * NN * HH;
        int head = (n0 + wcol) >> 6;
        float alj[4], arj[4];
        #pragma unroll
        for (int j = 0; j < 4; j++) {
            int gcol = n0 + wcol + j * 16 + l16;
            alj[j] = al[gcol];
            arj[j] = ar[gcol];
        }
        #pragma unroll
        for (int i = 0; i < 4; i++) {
            #pragma unroll
            for (int reg = 0; reg < 4; reg++) {
                int row = m0 + wrow + i * 16 + q * 4 + reg;
                float pl = 0.f, pr = 0.f;
                #pragma unroll
                for (int j = 0; j < 4; j++) {
                    pl = fmaf(acc[i][j][reg], alj[j], pl);
                    pr = fmaf(acc[i][j][reg], arj[j], pr);
                }
                #pragma unroll
                for (int m = 1; m < 16; m <<= 1) {
                    pl += __shfl_xor(pl, m, 64);
                    pr += __shfl_xor(pr, m, 64);
                }
                if (l16 == 0 && row < M) {
                    elp[(size_t)row * HH + head] = pl;
                    erp[(size_t)row * HH + head] = pr;
                }
            }
        }
    }
}

// ---------------- fused softmax + aggregation (r4-proven config) ----------------
// wave per node (4 nodes/block); lane owns 4 channels (one uint2 = 8 B).
// 4-edge software pipeline; per-lane redundant exp (free on SIMD); scalar
// el gather (4B, 16-lane HW broadcast per head group). r5 (exp de-dup via
// shfl) and r6 (8-edge + el float4) both regressed: this kernel sits on the
// ~3.2 TB/s random-gather plateau and lives off occupancy (VGPR 36, ~58%).
__global__ __launch_bounds__(256) void aggregate_fused(
    const ushort* __restrict__ feat16, const float* __restrict__ el,
    const float* __restrict__ er, const int* __restrict__ row_ptr,
    const int* __restrict__ csr_src, const float* __restrict__ bias,
    ushort* __restrict__ hout, int relu) {
    int wv = threadIdx.x >> 6, lane = threadIdx.x & 63;
    int node = blockIdx.x * 4 + wv;
    if (node >= NN) return;
    int c0 = lane * 4;
    int h = lane >> 4;
    float t0 = 0.f, t1 = 0.f, t2 = 0.f, t3 = 0.f;
    #pragma unroll
    for (int r = 0; r < RR; r++) {
        const int* rp = row_ptr + r * (NN + 1);
        int beg = rp[node], end = rp[node + 1];
        const ushort* fr = feat16 + (size_t)r * NN * CDIM;
        const float* elr = el + (size_t)r * NN * HH;
        float ern = er[((size_t)r * NN + node) * HH + h];
        const int* cs = csr_src + (size_t)r * EE;
        float p0 = 0.f, p1 = 0.f, p2 = 0.f, p3 = 0.f, ssum = 0.f;
        int e = beg;
        for (; e + 4 <= end; e += 4) {
            int s0 = cs[e], s1 = cs[e + 1], s2 = cs[e + 2], s3 = cs[e + 3];
            float x0 = elr[s0 * HH + h];
            float x1 = elr[s1 * HH + h];
            float x2 = elr[s2 * HH + h];
            float x3 = elr[s3 * HH + h];
            uint2 f0 = *(const uint2*)(fr + (size_t)s0 * CDIM + c0);
            uint2 f1 = *(const uint2*)(fr + (size_t)s1 * CDIM + c0);
            uint2 f2 = *(const uint2*)(fr + (size_t)s2 * CDIM + c0);
            uint2 f3 = *(const uint2*)(fr + (size_t)s3 * CDIM + c0);
            x0 += ern; x1 += ern; x2 += ern; x3 += ern;
            x0 = x0 > 0.f ? x0 : NEG * x0;
            x1 = x1 > 0.f ? x1 : NEG * x1;
            x2 = x2 > 0.f ? x2 : NEG * x2;
            x3 = x3 > 0.f ? x3 : NEG * x3;
            float a0 = __expf(x0), a1 = __expf(x1), a2 = __expf(x2), a3 = __expf(x3);
            ssum += a0 + a1 + a2 + a3;
            p0 = fmaf(a0, bflo(f0.x), p0); p1 = fmaf(a0, bfhi(f0.x), p1);
            p2 = fmaf(a0, bflo(f0.y), p2); p3 = fmaf(a0, bfhi(f0.y), p3);
            p0 = fmaf(a1, bflo(f1.x), p0); p1 = fmaf(a1, bfhi(f1.x), p1);
            p2 = fmaf(a1, bflo(f1.y), p2); p3 = fmaf(a1, bfhi(f1.y), p3);
            p0 = fmaf(a2, bflo(f2.x), p0); p1 = fmaf(a2, bfhi(f2.x), p1);
            p2 = fmaf(a2, bflo(f2.y), p2); p3 = fmaf(a2, bfhi(f2.y), p3);
            p0 = fmaf(a3, bflo(f3.x), p0); p1 = fmaf(a3, bfhi(f3.x), p1);
            p2 = fmaf(a3, bflo(f3.y), p2); p3 = fmaf(a3, bfhi(f3.y), p3);
        }
        for (; e < end; e++) {
            int s = cs[e];
            float x = elr[s * HH + h] + ern;
            x = x > 0.f ? x : NEG * x;
            float a = __expf(x);
            uint2 f = *(const uint2*)(fr + (size_t)s * CDIM + c0);
            ssum += a;
            p0 = fmaf(a, bflo(f.x), p0); p1 = fmaf(a, bfhi(f.x), p1);
            p2 = fmaf(a, bflo(f.y), p2); p3 = fmaf(a, bfhi(f.y), p3);
        }
        float is = (end > beg) ? 1.f / ssum : 0.f;
        t0 += p0 * is + bias[r * CDIM + c0];
        t1 += p1 * is + bias[r * CDIM + c0 + 1];
        t2 += p2 * is + bias[r * CDIM + c0 + 2];
        t3 += p3 * is + bias[r * CDIM + c0 + 3];
    }
    if (relu) {
        t0 = fmaxf(t0, 0.f); t1 = fmaxf(t1, 0.f);
        t2 = fmaxf(t2, 0.f); t3 = fmaxf(t3, 0.f);
    }
    uint2 o;
    o.x = (uint)f2bf(t0) | ((uint)f2bf(t1) << 16);
    o.y = (uint)f2bf(t2) | ((uint)f2bf(t3) << 16);
    *(uint2*)(hout + (size_t)node * CDIM + c0) = o;
}

// ---------------- launcher ----------------

extern "C" void kernel_launch(void* const* d_in, const int* in_sizes, int n_in,
                              void* d_out, int out_size, void* d_ws, size_t ws_size,
                              hipStream_t stream) {
    const float* x        = (const float*)d_in[0];
    const int*   edge_src = (const int*)d_in[1];
    const int*   edge_dst = (const int*)d_in[2];
    const float* W        = (const float*)d_in[3];
    const float* attn_l   = (const float*)d_in[4];
    const float* attn_r   = (const float*)d_in[5];
    const float* bias     = (const float*)d_in[6];
    const float* fc_w     = (const float*)d_in[7];
    const float* fc_b     = (const float*)d_in[8];
    float* out = (float*)d_out;

    char* ws = (char*)d_ws;
    size_t off = 0;
    auto alloc = [&](size_t bytes) {
        void* p = ws + off;
        off = (off + bytes + 255) & ~(size_t)255;
        return p;
    };
    ushort* x16    = (ushort*)alloc((size_t)NN * CDIM * 2);
    ushort* h16    = (ushort*)alloc((size_t)NN * CDIM * 2);
    ushort* feat16 = (ushort*)alloc((size_t)RR * NN * CDIM * 2);
    ushort* Wt16   = (ushort*)alloc((size_t)LL * RR * CDIM * CDIM * 2);
    ushort* fct16  = (ushort*)alloc((size_t)OUTD * CDIM * 2);
    float* el      = (float*)alloc((size_t)RR * NN * HH * 4);
    float* er      = (float*)alloc((size_t)RR * NN * HH * 4);
    int* row_ptr   = (int*)alloc((size_t)RR * (NN + 1) * 4);
    int* cursor    = (int*)alloc((size_t)RR * (NN + 1) * 4);
    int* csr_src   = (int*)alloc((size_t)RR * EE * 4);
    int* deg       = (int*)alloc((size_t)RR * NN * 4);

    // CSR build
    zero_ints<<<dim3((RR * NN + 1023) / 1024), dim3(1024), 0, stream>>>(deg, RR * NN);
    count_deg<<<dim3((RR * EE + 255) / 256), dim3(256), 0, stream>>>(edge_dst, deg);
    scan_kernel<<<dim3(RR), dim3(1024), 0, stream>>>(deg, row_ptr);
    hipMemcpyAsync(cursor, row_ptr, (size_t)RR * (NN + 1) * 4,
                   hipMemcpyDeviceToDevice, stream);
    fill_csr<<<dim3((RR * EE + 255) / 256), dim3(256), 0, stream>>>(
        edge_src, edge_dst, cursor, csr_src);

    // dtype prep
    cvt_bf16x4<<<dim3((NN * CDIM / 4 + 255) / 256), dim3(256), 0, stream>>>(x, x16, NN * CDIM / 4);
    prep_Wt<<<dim3(CDIM / 32, CDIM / 32, LL * RR), dim3(32, 8), 0, stream>>>(W, Wt16, CDIM, CDIM);
    prep_Wt<<<dim3(CDIM / 32, OUTD / 32, 1), dim3(32, 8), 0, stream>>>(fc_w, fct16, CDIM, OUTD);

    const ushort* hin = x16;
    for (int l = 0; l < LL; l++) {
        const ushort* Wl = Wt16 + (size_t)l * RR * CDIM * CDIM;
        dim3 g((NN + TM - 1) / TM, CDIM / TN, RR);
        gemm_bf16<<<g, dim3(256), 0, stream>>>(hin, Wl, feat16, NN, CDIM, CDIM,
                                               (long)CDIM * CDIM, (long)NN * CDIM, nullptr, 0,
                                               attn_l + (size_t)l * RR * CDIM,
                                               attn_r + (size_t)l * RR * CDIM, el, er);
        aggregate_fused<<<dim3(NN / 4), dim3(256), 0, stream>>>(
            feat16, el, er, row_ptr, csr_src, bias + (size_t)l * RR * CDIM,
            h16, (l != LL - 1) ? 1 : 0);
        hin = h16;
    }
    dim3 gf((NN + TM - 1) / TM, OUTD / TN, 1);
    gemm_bf16<<<gf, dim3(256), 0, stream>>>(h16, fct16, out, NN, CDIM, OUTD,
                                            0, 0, fc_b, 1, nullptr, nullptr, nullptr, nullptr);
}

// Round 8
// 513.447 us; speedup vs baseline: 1.3645x; 1.0411x over previous
//
#include <hip/hip_runtime.h>
#include <math.h>

#define NN 20000
#define NN_PAD 20096   // NN rounded up to TM; pad rows are garbage, never stored
#define EE 320000
#define RR 3
#define LL 3
#define HH 4
#define DD 64
#define CDIM 256   // H*D == IN
#define OUTD 128
#define NEG 0.2f

typedef float f32x4 __attribute__((ext_vector_type(4)));
typedef short sh8 __attribute__((ext_vector_type(8)));

__device__ __forceinline__ ushort f2bf(float f) {
    union { float f; uint u; } v; v.f = f;
    uint r = (v.u + 0x7FFF + ((v.u >> 16) & 1)) >> 16;   // RNE
    return (ushort)r;
}
__device__ __forceinline__ float bf2f(ushort u) {
    union { uint u; float f; } v; v.u = ((uint)u) << 16;
    return v.f;
}
__device__ __forceinline__ float bflo(uint p) { return bf2f((ushort)(p & 0xffff)); }
__device__ __forceinline__ float bfhi(uint p) { return bf2f((ushort)(p >> 16)); }

// async global->LDS, 16 B per lane; LDS dst is wave-uniform base + lane*16
__device__ __forceinline__ void glds16(const ushort* g, ushort* l) {
    __builtin_amdgcn_global_load_lds(
        (const __attribute__((address_space(1))) void*)g,
        (__attribute__((address_space(3))) void*)l, 16, 0, 0);
}

// ---------------- CSR build ----------------

__global__ void count_deg(const int* __restrict__ edge_dst, int* __restrict__ deg) {
    int i = blockIdx.x * blockDim.x + threadIdx.x;
    if (i >= RR * EE) return;
    int r = i / EE;
    atomicAdd(&deg[r * NN + edge_dst[i]], 1);
}

// one block per relation; wave-shfl scan; writes row_ptr AND cursor copy.
__global__ __launch_bounds__(1024) void scan_kernel(
    const int* __restrict__ deg, int* __restrict__ row_ptr, int* __restrict__ cursor) {
    int r = blockIdx.x;
    const int* d = deg + r * NN;
    int* rp = row_ptr + r * (NN + 1);
    int* cur = cursor + r * (NN + 1);
    __shared__ int wsum[16];
    int lane = threadIdx.x & 63, wv = threadIdx.x >> 6;
    if (threadIdx.x == 0) { rp[0] = 0; cur[0] = 0; }
    int carry = 0;
    for (int base = 0; base < NN; base += 1024) {
        int i = base + threadIdx.x;
        int v = (i < NN) ? d[i] : 0;
        int s = v;
        #pragma unroll
        for (int off = 1; off < 64; off <<= 1) {
            int n = __shfl_up(s, off, 64);
            if (lane >= off) s += n;
        }
        if (lane == 63) wsum[wv] = s;
        __syncthreads();
        if (wv == 0) {
            int ws = (lane < 16) ? wsum[lane] : 0;
            #pragma unroll
            for (int off = 1; off < 16; off <<= 1) {
                int n = __shfl_up(ws, off, 64);
                if (lane >= off) ws += n;
            }
            if (lane < 16) wsum[lane] = ws;
        }
        __syncthreads();
        int incl = carry + (wv ? wsum[wv - 1] : 0) + s;
        if (i < NN) { rp[i + 1] = incl; cur[i + 1] = incl; }
        carry += wsum[15];
        __syncthreads();
    }
}

// cursor[] starts as a copy of row_ptr; atomically bump to place each edge.
__global__ void fill_csr(const int* __restrict__ edge_src, const int* __restrict__ edge_dst,
                         int* __restrict__ cursor, int* __restrict__ csr_src) {
    int i = blockIdx.x * blockDim.x + threadIdx.x;
    if (i >= RR * EE) return;
    int r = i / EE;
    int dst = edge_dst[i];
    int pos = atomicAdd(&cursor[r * (NN + 1) + dst], 1);
    csr_src[r * EE + pos] = edge_src[i];
}

// ---------------- dtype prep ----------------

__global__ void cvt_bf16x4(const float* __restrict__ in, ushort* __restrict__ out, int n4) {
    int i = blockIdx.x * blockDim.x + threadIdx.x;
    if (i >= n4) return;
    float4 v = *(const float4*)(in + (size_t)i * 4);
    ushort4 o;
    o.x = f2bf(v.x); o.y = f2bf(v.y); o.z = f2bf(v.z); o.w = f2bf(v.w);
    *(ushort4*)(out + (size_t)i * 4) = o;
}

// transpose fp32 [K][N] -> bf16 [N][K]; z<LL*RR: W matrices; z==LL*RR: fc_w.
__global__ void prep_all(const float* __restrict__ W, const float* __restrict__ fc_w,
                         ushort* __restrict__ Wt, ushort* __restrict__ fct) {
    __shared__ float tile[32][33];
    int z = blockIdx.z;
    const float* src;
    ushort* dst;
    int N;
    if (z < LL * RR) {
        src = W + (size_t)z * CDIM * CDIM;
        dst = Wt + (size_t)z * CDIM * CDIM;
        N = CDIM;
    } else {
        src = fc_w;
        dst = fct;
        N = OUTD;
    }
    int kb = blockIdx.x * 32, nb = blockIdx.y * 32;
    if (nb >= N) return;
    for (int yy = threadIdx.y; yy < 32; yy += 8)
        tile[yy][threadIdx.x] = src[(size_t)(kb + yy) * N + nb + threadIdx.x];
    __syncthreads();
    for (int yy = threadIdx.y; yy < 32; yy += 8)
        dst[(size_t)(nb + yy) * CDIM + kb + threadIdx.x] = f2bf(tile[threadIdx.x][yy]);
}

// ---------------- bf16 MFMA GEMM (+ fused el/er epilogue) ----------------
// C[M][Ncol] = A[M][K](bf16) @ Bt[Ncol][K](bf16)^T ; 128x128 tile, BK=32.
// Staging via global_load_lds (16 B/lane, no VGPR round-trip). LDS layout is
// lane-linear [row][32 shorts] with the 16 B chunk index XOR-swizzled by
// (row>>1)&3 on BOTH the global fetch and the fragment read: banks repeat
// with period 8 across the 16 fragment lanes -> 2-way (free). A-source rows
// are padded to NN_PAD so glds (unpredicated) never reads OOB.

#define TM 128
#define TN 128
#define TK 32

__global__ __launch_bounds__(256) void gemm_bf16(
    const ushort* __restrict__ A, const ushort* __restrict__ Bt0, void* __restrict__ C0,
    int M, int K, int Ncol, long strideB, long strideC,
    const float* __restrict__ bias, int out_fp32,
    const float* __restrict__ al_all, const float* __restrict__ ar_all,
    float* __restrict__ el_all, float* __restrict__ er_all) {
    __shared__ alignas(16) ushort As[TM * 32];
    __shared__ alignas(16) ushort Bs[TN * 32];
    const ushort* Bt = Bt0 + (size_t)blockIdx.z * strideB;
    int m0 = blockIdx.x * TM, n0 = blockIdx.y * TN;
    int t = threadIdx.x;
    int wave = t >> 6, lane = t & 63;
    int q = lane >> 4, l16 = lane & 15;
    int wrow = (wave >> 1) * 64, wcol = (wave & 1) * 64;

    // fragment LDS offsets (shorts), k0-independent; chunk swizzle = q ^ ((l16>>1)&3)
    int sw = (q ^ ((l16 >> 1) & 3)) * 8;
    int a_off[4], b_off[4];
    #pragma unroll
    for (int i = 0; i < 4; i++) {
        a_off[i] = (wrow + i * 16 + l16) * 32 + sw;
        b_off[i] = (wcol + i * 16 + l16) * 32 + sw;
    }
    // staging: qid in [0,512): row = qid>>2, global chunk = (qid&3) ^ ((row>>1)&3)
    int row_a = t >> 2;
    int ch_a  = ((t & 3) ^ ((row_a >> 1) & 3)) * 8;

    f32x4 acc[4][4];
    #pragma unroll
    for (int i = 0; i < 4; i++)
        #pragma unroll
        for (int j = 0; j < 4; j++)
            #pragma unroll
            for (int k = 0; k < 4; k++) acc[i][j][k] = 0.f;

    for (int k0 = 0; k0 < K; k0 += TK) {
        #pragma unroll
        for (int s = 0; s < 2; s++) {
            int qid = t + s * 256;
            int row = row_a + s * 64;
            glds16(A + (size_t)(m0 + row) * K + k0 + ch_a, As + qid * 8);
        }
        #pragma unroll
        for (int s = 0; s < 2; s++) {
            int qid = t + s * 256;
            int row = row_a + s * 64;
            glds16(Bt + (size_t)(n0 + row) * K + k0 + ch_a, Bs + qid * 8);
        }
        __syncthreads();
        sh8 af[4], bfr[4];
        #pragma unroll
        for (int i = 0; i < 4; i++) af[i] = *(const sh8*)(As + a_off[i]);
        #pragma unroll
        for (int j = 0; j < 4; j++) bfr[j] = *(const sh8*)(Bs + b_off[j]);
        #pragma unroll
        for (int i = 0; i < 4; i++)
            #pragma unroll
            for (int j = 0; j < 4; j++)
                acc[i][j] = __builtin_amdgcn_mfma_f32_16x16x32_bf16(af[i], bfr[j], acc[i][j], 0, 0, 0);
        __syncthreads();
    }

    // epilogue: C/D layout col=lane&15, row=q*4+reg
    if (out_fp32) {
        float* C = (float*)C0 + (size_t)blockIdx.z * strideC;
        #pragma unroll
        for (int i = 0; i < 4; i++) {
            #pragma unroll
            for (int reg = 0; reg < 4; reg++) {
                int row = m0 + wrow + i * 16 + q * 4 + reg;
                if (row >= M) continue;
                #pragma unroll
                for (int j = 0; j < 4; j++) {
                    int col = n0 + wcol + j * 16 + l16;
                    float v = acc[i][j][reg];
                    if (bias) v += bias[col];
                    C[(size_t)row * Ncol + col] = v;
                }
            }
        }
    } else {
        ushort* C = (ushort*)C0 + (size_t)blockIdx.z * strideC;
        #pragma unroll
        for (int i = 0; i < 4; i++) {
            #pragma unroll
            for (int reg = 0; reg < 4; reg++) {
                int row = m0 + wrow + i * 16 + q * 4 + reg;
                if (row >= M) continue;
                #pragma unroll
                for (int j = 0; j < 4; j++) {
                    int col = n0 + wcol + j * 16 + l16;
                    C[(size_t)row * Ncol + col] = f2bf(acc[i][j][reg]);
                }
            }
        }
    }

    if (el_all) {
        const float* al = al_all + (size_t)blockIdx.z * CDIM;
        const float* ar = ar_all + (size_t)blockIdx.z * CDIM;
        float* elp = el_all + (size_t)blockIdx.z * NN * HH;
        float* erp = er_all + (size_t)blockIdx.z * NN * HH;
        int head = (n0 + wcol) >> 6;
        float alj[4], arj[4];
        #pragma unroll
        for (int j = 0; j < 4; j++) {
            int gcol = n0 + wcol + j * 16 + l16;
            alj[j] = al[gcol];
            arj[j] = ar[gcol];
        }
        #pragma unroll
        for (int i = 0; i < 4; i++) {
            #pragma unroll
            for (int reg = 0; reg < 4; reg++) {
                int row = m0 + wrow + i * 16 + q * 4 + reg;
                float pl = 0.f, pr = 0.f;
                #pragma unroll
                for (int j = 0; j < 4; j++) {
                    pl = fmaf(acc[i][j][reg], alj[j], pl);
                    pr = fmaf(acc[i][j][reg], arj[j], pr);
                }
                #pragma unroll
                for (int m = 1; m < 16; m <<= 1) {
                    pl += __shfl_xor(pl, m, 64);
                    pr += __shfl_xor(pr, m, 64);
                }
                if (l16 == 0 && row < M) {
                    elp[(size_t)row * HH + head] = pl;
                    erp[(size_t)row * HH + head] = pr;
                }
            }
        }
    }
}

// ---------------- fused softmax + aggregation (r4-proven config) ----------------
// wave per node (4 nodes/block); lane owns 4 channels (one uint2 = 8 B).
// 4-edge software pipeline; per-lane redundant exp (free on SIMD); scalar
// el gather (4B, 16-lane HW broadcast per head group). r5 (exp de-dup via
// shfl) and r6 (8-edge + el float4) both regressed: this kernel sits on the
// ~3.2 TB/s random-gather plateau and lives off occupancy (VGPR 36, ~58%).
__global__ __launch_bounds__(256) void aggregate_fused(
    const ushort* __restrict__ feat16, const float* __restrict__ el,
    const float* __restrict__ er, const int* __restrict__ row_ptr,
    const int* __restrict__ csr_src, const float* __restrict__ bias,
    ushort* __restrict__ hout, int relu) {
    int wv = threadIdx.x >> 6, lane = threadIdx.x & 63;
    int node = blockIdx.x * 4 + wv;
    if (node >= NN) return;
    int c0 = lane * 4;
    int h = lane >> 4;
    float t0 = 0.f, t1 = 0.f, t2 = 0.f, t3 = 0.f;
    #pragma unroll
    for (int r = 0; r < RR; r++) {
        const int* rp = row_ptr + r * (NN + 1);
        int beg = rp[node], end = rp[node + 1];
        const ushort* fr = feat16 + (size_t)r * NN * CDIM;
        const float* elr = el + (size_t)r * NN * HH;
        float ern = er[((size_t)r * NN + node) * HH + h];
        const int* cs = csr_src + (size_t)r * EE;
        float p0 = 0.f, p1 = 0.f, p2 = 0.f, p3 = 0.f, ssum = 0.f;
        int e = beg;
        for (; e + 4 <= end; e += 4) {
            int s0 = cs[e], s1 = cs[e + 1], s2 = cs[e + 2], s3 = cs[e + 3];
            float x0 = elr[s0 * HH + h];
            float x1 = elr[s1 * HH + h];
            float x2 = elr[s2 * HH + h];
            float x3 = elr[s3 * HH + h];
            uint2 f0 = *(const uint2*)(fr + (size_t)s0 * CDIM + c0);
            uint2 f1 = *(const uint2*)(fr + (size_t)s1 * CDIM + c0);
            uint2 f2 = *(const uint2*)(fr + (size_t)s2 * CDIM + c0);
            uint2 f3 = *(const uint2*)(fr + (size_t)s3 * CDIM + c0);
            x0 += ern; x1 += ern; x2 += ern; x3 += ern;
            x0 = x0 > 0.f ? x0 : NEG * x0;
            x1 = x1 > 0.f ? x1 : NEG * x1;
            x2 = x2 > 0.f ? x2 : NEG * x2;
            x3 = x3 > 0.f ? x3 : NEG * x3;
            float a0 = __expf(x0), a1 = __expf(x1), a2 = __expf(x2), a3 = __expf(x3);
            ssum += a0 + a1 + a2 + a3;
            p0 = fmaf(a0, bflo(f0.x), p0); p1 = fmaf(a0, bfhi(f0.x), p1);
            p2 = fmaf(a0, bflo(f0.y), p2); p3 = fmaf(a0, bfhi(f0.y), p3);
            p0 = fmaf(a1, bflo(f1.x), p0); p1 = fmaf(a1, bfhi(f1.x), p1);
            p2 = fmaf(a1, bflo(f1.y), p2); p3 = fmaf(a1, bfhi(f1.y), p3);
            p0 = fmaf(a2, bflo(f2.x), p0); p1 = fmaf(a2, bfhi(f2.x), p1);
            p2 = fmaf(a2, bflo(f2.y), p2); p3 = fmaf(a2, bfhi(f2.y), p3);
            p0 = fmaf(a3, bflo(f3.x), p0); p1 = fmaf(a3, bfhi(f3.x), p1);
            p2 = fmaf(a3, bflo(f3.y), p2); p3 = fmaf(a3, bfhi(f3.y), p3);
        }
        for (; e < end; e++) {
            int s = cs[e];
            float x = elr[s * HH + h] + ern;
            x = x > 0.f ? x : NEG * x;
            float a = __expf(x);
            uint2 f = *(const uint2*)(fr + (size_t)s * CDIM + c0);
            ssum += a;
            p0 = fmaf(a, bflo(f.x), p0); p1 = fmaf(a, bfhi(f.x), p1);
            p2 = fmaf(a, bflo(f.y), p2); p3 = fmaf(a, bfhi(f.y), p3);
        }
        float is = (end > beg) ? 1.f / ssum : 0.f;
        t0 += p0 * is + bias[r * CDIM + c0];
        t1 += p1 * is + bias[r * CDIM + c0 + 1];
        t2 += p2 * is + bias[r * CDIM + c0 + 2];
        t3 += p3 * is + bias[r * CDIM + c0 + 3];
    }
    if (relu) {
        t0 = fmaxf(t0, 0.f); t1 = fmaxf(t1, 0.f);
        t2 = fmaxf(t2, 0.f); t3 = fmaxf(t3, 0.f);
    }
    uint2 o;
    o.x = (uint)f2bf(t0) | ((uint)f2bf(t1) << 16);
    o.y = (uint)f2bf(t2) | ((uint)f2bf(t3) << 16);
    *(uint2*)(hout + (size_t)node * CDIM + c0) = o;
}

// ---------------- launcher ----------------

extern "C" void kernel_launch(void* const* d_in, const int* in_sizes, int n_in,
                              void* d_out, int out_size, void* d_ws, size_t ws_size,
                              hipStream_t stream) {
    const float* x        = (const float*)d_in[0];
    const int*   edge_src = (const int*)d_in[1];
    const int*   edge_dst = (const int*)d_in[2];
    const float* W        = (const float*)d_in[3];
    const float* attn_l   = (const float*)d_in[4];
    const float* attn_r   = (const float*)d_in[5];
    const float* bias     = (const float*)d_in[6];
    const float* fc_w     = (const float*)d_in[7];
    const float* fc_b     = (const float*)d_in[8];
    float* out = (float*)d_out;

    char* ws = (char*)d_ws;
    size_t off = 0;
    auto alloc = [&](size_t bytes) {
        void* p = ws + off;
        off = (off + bytes + 255) & ~(size_t)255;
        return p;
    };
    ushort* x16    = (ushort*)alloc((size_t)NN_PAD * CDIM * 2);  // padded: glds A-source
    ushort* h16    = (ushort*)alloc((size_t)NN_PAD * CDIM * 2);  // padded: glds A-source
    ushort* feat16 = (ushort*)alloc((size_t)RR * NN * CDIM * 2);
    ushort* Wt16   = (ushort*)alloc((size_t)LL * RR * CDIM * CDIM * 2);
    ushort* fct16  = (ushort*)alloc((size_t)OUTD * CDIM * 2);
    float* el      = (float*)alloc((size_t)RR * NN * HH * 4);
    float* er      = (float*)alloc((size_t)RR * NN * HH * 4);
    int* row_ptr   = (int*)alloc((size_t)RR * (NN + 1) * 4);
    int* cursor    = (int*)alloc((size_t)RR * (NN + 1) * 4);
    int* csr_src   = (int*)alloc((size_t)RR * EE * 4);
    int* deg       = (int*)alloc((size_t)RR * NN * 4);

    // CSR build
    hipMemsetAsync(deg, 0, (size_t)RR * NN * 4, stream);
    count_deg<<<dim3((RR * EE + 255) / 256), dim3(256), 0, stream>>>(edge_dst, deg);
    scan_kernel<<<dim3(RR), dim3(1024), 0, stream>>>(deg, row_ptr, cursor);
    fill_csr<<<dim3((RR * EE + 255) / 256), dim3(256), 0, stream>>>(
        edge_src, edge_dst, cursor, csr_src);

    // dtype prep
    cvt_bf16x4<<<dim3((NN * CDIM / 4 + 255) / 256), dim3(256), 0, stream>>>(x, x16, NN * CDIM / 4);
    prep_all<<<dim3(CDIM / 32, CDIM / 32, LL * RR + 1), dim3(32, 8), 0, stream>>>(
        W, fc_w, Wt16, fct16);

    const ushort* hin = x16;
    for (int l = 0; l < LL; l++) {
        const ushort* Wl = Wt16 + (size_t)l * RR * CDIM * CDIM;
        dim3 g(NN_PAD / TM, CDIM / TN, RR);
        gemm_bf16<<<g, dim3(256), 0, stream>>>(hin, Wl, feat16, NN, CDIM, CDIM,
                                               (long)CDIM * CDIM, (long)NN * CDIM, nullptr, 0,
                                               attn_l + (size_t)l * RR * CDIM,
                                               attn_r + (size_t)l * RR * CDIM, el, er);
        aggregate_fused<<<dim3(NN / 4), dim3(256), 0, stream>>>(
            feat16, el, er, row_ptr, csr_src, bias + (size_t)l * RR * CDIM,
            h16, (l != LL - 1) ? 1 : 0);
        hin = h16;
    }
    dim3 gf(NN_PAD / TM, OUTD / TN, 1);
    gemm_bf16<<<gf, dim3(256), 0, stream>>>(h16, fct16, out, NN, CDIM, OUTD,
                                            0, 0, fc_b, 1, nullptr, nullptr, nullptr, nullptr);
}